// Round 15
// baseline (92.379 us; speedup 1.0000x reference)
//
#include <hip/hip_runtime.h>
#include <hip/hip_bf16.h>
#include <float.h>

#define DIN   768
#define DSAE  16384
#define K_    32
#define CAND  64      // refinement candidate count
#define KTOT  2304
#define TD    12288   // 16*768
#define KSPLIT 4
#define NCH   18      // chunks of 32 per ksplit

typedef __attribute__((ext_vector_type(8))) short bf16x8;
typedef __attribute__((ext_vector_type(4))) float f32x4;

__device__ __forceinline__ short f2bf(float f) {      // RNE f32->bf16
    unsigned u = __float_as_uint(f);
    u += 0x7FFFu + ((u >> 16) & 1u);
    return (short)(u >> 16);
}

__device__ __forceinline__ void frag_store(short* frag, int k, int b, float val) {
    int c = k >> 5, kk = k & 31;
    size_t idx = (((size_t)(c * 2 + (b >> 4)) * 64) + (((kk >> 3) << 4) | (b & 15))) * 8
               + (kk & 7);
    frag[idx] = f2bf(val);
}

// ---- Kernel 1: prep (4-way t-split) — A_T fp32 + bf16 MFMA B-fragments ----
__global__ __launch_bounds__(256) void prep_kernel(const float* __restrict__ x,
                                                   float* __restrict__ A_T,
                                                   short* __restrict__ frag,
                                                   float* __restrict__ out0) {
    int g = blockIdx.x * 256 + threadIdx.x;      // 0..98303
    int pair = g >> 2, q = g & 3;
    int b = pair / DIN;
    int d = pair - b * DIN;
    const float* xp = x + (size_t)b * TD + d;

    float v0 = xp[(4 * q + 0) * DIN];
    float v1 = xp[(4 * q + 1) * DIN];
    float v2 = xp[(4 * q + 2) * DIN];
    float v3 = xp[(4 * q + 3) * DIN];
    float S = v0 + v1 + v2 + v3;
    S += __shfl_xor(S, 1, 64);
    S += __shfl_xor(S, 2, 64);
    float xf = __shfl_xor(v0, 1, 64);            // q1 <- q0's x[b,0,d]
    float xl = __shfl_xor(v3, 1, 64);            // q2 <- q3's x[b,15,d]

    int base = d * 96 + b;                       // (d*3+j)*32 + b
    int k0 = 3 * d;
    if (q == 0) {
        A_T[base + 32] = S;                      // j=1
    } else if (q == 1) {
        float u2 = S - xf;                       // j=2
        A_T[base + 64] = u2;
        frag_store(frag, k0 + 2, b, u2);
    } else if (q == 2) {
        float u0 = S - xl;                       // j=0
        A_T[base] = u0;
        frag_store(frag, k0, b, u0);
    } else {
        frag_store(frag, k0 + 1, b, S);          // j=1
    }
    if (g == 0) *out0 = 0.f;
}

// ---- Kernel 2: encode GEMM via MFMA 16x16x32 bf16 — no LDS, no barriers ----
// grid 1024 x 256 (16 waves/CU): wave = one 16-row W strip x one k-quarter.
__global__ __launch_bounds__(256, 4) void enc_mfma_kernel(
    const float* __restrict__ W,      // conv_w (16384 x 2304)
    const short* __restrict__ frag,   // (72 x 2 x 64 x 8) bf16
    float* __restrict__ partial)      // (4 x 32 x 16384)
{
    const int tid  = threadIdx.x;
    const int bid  = blockIdx.x;
    const int ks   = bid & 3;
    const int l    = tid & 63;
    const int w    = tid >> 6;
    const int strip = (bid >> 2) * 4 + w;        // 0..1023
    const int s0    = strip << 4;
    const int row   = s0 + (l & 15);
    const int klane = (l >> 4) << 3;

    const float* wrow = W + (size_t)row * KTOT;

    f32x4 acc0 = {0.f, 0.f, 0.f, 0.f};
    f32x4 acc1 = {0.f, 0.f, 0.f, 0.f};

    #pragma unroll 3
    for (int ch = 0; ch < NCH; ++ch) {
        const int cg = ks * NCH + ch;
        const int kb = (cg << 5) + klane;
        const float4 wa = *(const float4*)&wrow[kb];
        const float4 wb = *(const float4*)&wrow[kb + 4];
        bf16x8 wf;
        wf[0] = f2bf(wa.x); wf[1] = f2bf(wa.y); wf[2] = f2bf(wa.z); wf[3] = f2bf(wa.w);
        wf[4] = f2bf(wb.x); wf[5] = f2bf(wb.y); wf[6] = f2bf(wb.z); wf[7] = f2bf(wb.w);
        const bf16x8 a0 = *(const bf16x8*)&frag[((size_t)(cg * 2    ) * 64 + l) * 8];
        const bf16x8 a1 = *(const bf16x8*)&frag[((size_t)(cg * 2 + 1) * 64 + l) * 8];
        acc0 = __builtin_amdgcn_mfma_f32_16x16x32_bf16(wf, a0, acc0, 0, 0, 0);
        acc1 = __builtin_amdgcn_mfma_f32_16x16x32_bf16(wf, a1, acc1, 0, 0, 0);
    }

    // C/D: col=lane&15 (b), row=(lane>>4)*4+reg (s)  [m89]; rows consecutive -> float4
    const int bcol  = l & 15;
    const int sbase = s0 + ((l >> 4) << 2);
    float* p0 = partial + ((size_t)(ks * 32) + bcol) * DSAE + sbase;
    float* p1 = p0 + (size_t)16 * DSAE;
    *(float4*)p0 = make_float4(acc0[0], acc0[1], acc0[2], acc0[3]);
    *(float4*)p1 = make_float4(acc1[0], acc1[1], acc1[2], acc1[3]);
}

// ---- Kernel 3: fused combine + radix top-64 + exact fp32 refine + scatter ----
__global__ __launch_bounds__(1024, 1) void topk_kernel(
    const float* __restrict__ partial, // (4 x 32 x 16384)
    const float* __restrict__ b_enc,
    float* __restrict__ z,             // out: sparse z (32 x DSAE)
    const float* __restrict__ A_T,     // (2304 x 32) fp32 exact
    const float* __restrict__ W,       // conv_w
    float* __restrict__ sel_val,
    int*   __restrict__ sel_idx)
{
    __shared__ unsigned hist[256];
    __shared__ unsigned gsfx[65];
    __shared__ unsigned sfx[257];
    __shared__ int      sdelta;
    __shared__ unsigned scnt;
    __shared__ int      l_idx[CAND];
    __shared__ float    ex_val[CAND];
    __shared__ int      rnk[CAND];
    __shared__ int      eq_min;
    __shared__ float    A_col[KTOT];

    const int t = threadIdx.x;
    const int b = blockIdx.x;
    float* zrow = z + (size_t)b * DSAE;

    // combine in registers: pre = b_enc + sum_ks partial[ks]
    unsigned u[16];
    #pragma unroll
    for (int i = 0; i < 16; ++i) {
        const int col = t + (i << 10);
        float f = b_enc[col];
        #pragma unroll
        for (int ks = 0; ks < KSPLIT; ++ks)
            f += partial[(size_t)(ks * 32 + b) * DSAE + col];
        unsigned xb = __float_as_uint(f);
        u[i] = (xb & 0x80000000u) ? ~xb : (xb | 0x80000000u);
    }

    // ---- phase A: radix-select the CAND-th largest mapped value ----
    unsigned prefix = 0, pmask = 0;
    int need = CAND;
    for (int p = 0; p < 4; ++p) {
        const int shift = 24 - 8 * p;
        if (t < 256) hist[t] = 0;
        __syncthreads();
        #pragma unroll
        for (int i = 0; i < 16; ++i)
            if ((u[i] & pmask) == prefix)
                atomicAdd(&hist[(u[i] >> shift) & 255u], 1u);
        __syncthreads();
        if (t < 64) {
            unsigned s4 = hist[4*t] + hist[4*t+1] + hist[4*t+2] + hist[4*t+3];
            #pragma unroll
            for (int off = 1; off < 64; off <<= 1) {
                unsigned o = __shfl_down(s4, off, 64);
                if (t + off < 64) s4 += o;
            }
            gsfx[t] = s4;
            if (t == 0) gsfx[64] = 0;
        }
        __syncthreads();
        if (t < 256) {
            int q = t >> 2;
            unsigned acc = gsfx[q + 1];
            for (int d = 4*q + 3; d >= t; --d) acc += hist[d];
            sfx[t] = acc;
            if (t == 0) sfx[256] = 0;
        }
        __syncthreads();
        if (t < 256) {
            if (sfx[t] >= (unsigned)need && sfx[t + 1] < (unsigned)need) sdelta = t;
        }
        __syncthreads();
        const int dlt = sdelta;
        need  -= (int)sfx[dlt + 1];
        prefix |= ((unsigned)dlt) << shift;
        pmask  |= 0xFFu << shift;
        __syncthreads();
    }

    const unsigned ustar = prefix;
    if (t == 0) scnt = 0;
    __syncthreads();
    unsigned eqmask = 0;
    #pragma unroll
    for (int i = 0; i < 16; ++i) {
        int idx = t + (i << 10);
        if (u[i] > ustar) {
            unsigned s = atomicAdd(&scnt, 1u);
            l_idx[s] = idx;
        } else if (u[i] == ustar) {
            eqmask |= (1u << i);
        }
    }
    __syncthreads();
    const int needf = need;
    for (int r = 0; r < needf; ++r) {
        if (t == 0) eq_min = 0x7FFFFFFF;
        __syncthreads();
        #pragma unroll
        for (int i = 0; i < 16; ++i)
            if (eqmask & (1u << i)) atomicMin(&eq_min, t + (i << 10));
        __syncthreads();
        #pragma unroll
        for (int i = 0; i < 16; ++i)
            if ((eqmask & (1u << i)) && (t + (i << 10) == eq_min)) {
                eqmask &= ~(1u << i);
                unsigned s = atomicAdd(&scnt, 1u);
                l_idx[s] = eq_min;
            }
        __syncthreads();
    }

    // ---- stage A_T column b into LDS ----
    for (int q = t; q < KTOT; q += 1024) A_col[q] = A_T[q * 32 + b];
    __syncthreads();

    // ---- phase B: exact fp32 recompute of the 64 candidates ----
    {
        const int j = t >> 4, t16 = t & 15;
        const int cand = l_idx[j];
        const float* wr = W + (size_t)cand * KTOT;
        float s = 0.f;
        for (int q = t16; q < 576; q += 16) {
            const float4 wv = *(const float4*)&wr[q << 2];
            const int k4 = q << 2;
            s += wv.x * A_col[k4] + wv.y * A_col[k4 + 1]
               + wv.z * A_col[k4 + 2] + wv.w * A_col[k4 + 3];
        }
        s += __shfl_xor(s, 1, 64);
        s += __shfl_xor(s, 2, 64);
        s += __shfl_xor(s, 4, 64);
        s += __shfl_xor(s, 8, 64);
        if (t16 == 0) ex_val[j] = s + b_enc[cand];
    }
    __syncthreads();

    // ---- phase C: exact rank (value desc, idx asc), zero z, scatter ----
    if (t < CAND) {
        float v = ex_val[t]; int ix = l_idx[t];
        int r = 0;
        for (int j2 = 0; j2 < CAND; ++j2) {
            float v2 = ex_val[j2]; int ix2 = l_idx[j2];
            r += (v2 > v || (v2 == v && ix2 < ix)) ? 1 : 0;
        }
        rnk[t] = r;
    }
    __syncthreads();
    #pragma unroll
    for (int i = 0; i < 16; ++i) zrow[t + (i << 10)] = 0.f;
    __syncthreads();
    if (t < CAND && rnk[t] < K_) {
        int ix = l_idx[t];
        float v = ex_val[t];
        int pos = 0;
        for (int j2 = 0; j2 < CAND; ++j2)
            pos += (rnk[j2] < K_ && l_idx[j2] < ix) ? 1 : 0;
        float val = v > 0.f ? v : 0.f;
        zrow[ix] = val;
        sel_val[(b << 5) + pos] = val;
        sel_idx[(b << 5) + pos] = ix;
    }
}

// ---- Kernel 4: sparse decode + fused sq-err, atomic loss (768 x 128) ----
__global__ __launch_bounds__(128, 8) void decode_kernel(
    const float* __restrict__ W_dec,
    const float* __restrict__ b_dec,
    const float* __restrict__ x,
    const float* __restrict__ sel_val,
    const int*   __restrict__ sel_idx,
    float* __restrict__ xhat,          // d_out + 1
    float* __restrict__ out0)
{
    __shared__ float sv[K_];
    __shared__ int   si[K_];
    __shared__ float wsum[2];

    const int t     = threadIdx.x;
    const int blk   = blockIdx.x;
    const int b     = blk / 24;
    const int chunk = blk - b * 24;

    if (t < K_) { sv[t] = sel_val[(b << 5) + t]; si[t] = sel_idx[(b << 5) + t]; }
    __syncthreads();

    const int e = chunk * 512 + t * 4;
    float4 acc = *(const float4*)&b_dec[e];
    #pragma unroll 8
    for (int j = 0; j < K_; ++j) {
        const float val = sv[j];
        const float4 wd = *(const float4*)&W_dec[(size_t)si[j] * TD + e];
        acc.x += val * wd.x;
        acc.y += val * wd.y;
        acc.z += val * wd.z;
        acc.w += val * wd.w;
    }

    const size_t xo = (size_t)b * TD + e;
    xhat[xo + 0] = acc.x;
    xhat[xo + 1] = acc.y;
    xhat[xo + 2] = acc.z;
    xhat[xo + 3] = acc.w;

    const float4 xv = *(const float4*)&x[xo];
    float dx = acc.x - xv.x, dy = acc.y - xv.y;
    float dz = acc.z - xv.z, dw = acc.w - xv.w;
    float ss = dx * dx + dy * dy + dz * dz + dw * dw;
    #pragma unroll
    for (int off = 32; off > 0; off >>= 1) ss += __shfl_down(ss, off, 64);
    if ((t & 63) == 0) wsum[t >> 6] = ss;
    __syncthreads();
    if (t == 0)
        atomicAdd(out0, (wsum[0] + wsum[1]) * (1.0f / 512.0f));
}

extern "C" void kernel_launch(void* const* d_in, const int* in_sizes, int n_in,
                              void* d_out, int out_size, void* d_ws, size_t ws_size,
                              hipStream_t stream) {
    const float* x      = (const float*)d_in[0];
    const float* conv_w = (const float*)d_in[1];
    const float* b_enc  = (const float*)d_in[2];
    const float* W_dec  = (const float*)d_in[3];
    const float* b_dec  = (const float*)d_in[4];

    float* out  = (float*)d_out;
    float* xhat = out + 1;                        // (32,16,768)
    float* z    = out + 1 + 393216;               // (32,16384)

    float* partial_enc = (float*)d_ws;                           // 8.4 MB
    float* A_T         = (float*)((char*)d_ws + (12u << 20));    // 288 KB
    short* frag        = (short*)((char*)d_ws + (13u << 20));    // 147 KB
    float* sel_val     = (float*)((char*)d_ws + (14u << 20));
    int*   sel_idx     = (int*)  ((char*)d_ws + (14u << 20) + 4096);

    prep_kernel    <<<384,  256,  0, stream>>>(x, A_T, frag, out);
    enc_mfma_kernel<<<1024, 256,  0, stream>>>(conv_w, frag, partial_enc);
    topk_kernel    <<<32,   1024, 0, stream>>>(partial_enc, b_enc, z, A_T, conv_w,
                                               sel_val, sel_idx);
    decode_kernel  <<<768,  128,  0, stream>>>(W_dec, b_dec, x, sel_val, sel_idx, xhat, out);
}

// Round 16
// 82.931 us; speedup vs baseline: 1.1139x; 1.1139x over previous
//
#include <hip/hip_runtime.h>
#include <hip/hip_bf16.h>
#include <float.h>

#define DIN   768
#define DSAE  16384
#define K_    32
#define CAND  64      // refinement candidate count
#define KTOT  2304
#define TD    12288   // 16*768
#define KSPLIT 2
#define NCH   36      // chunks of 32 per ksplit

typedef __attribute__((ext_vector_type(8))) short bf16x8;
typedef __attribute__((ext_vector_type(4))) float f32x4;

__device__ __forceinline__ short f2bf(float f) {      // RNE f32->bf16
    unsigned u = __float_as_uint(f);
    u += 0x7FFFu + ((u >> 16) & 1u);
    return (short)(u >> 16);
}

__device__ __forceinline__ void frag_store(short* frag, int k, int b, float val) {
    int c = k >> 5, kk = k & 31;
    size_t idx = (((size_t)(c * 2 + (b >> 4)) * 64) + (((kk >> 3) << 4) | (b & 15))) * 8
               + (kk & 7);
    frag[idx] = f2bf(val);
}

// ---- Kernel 1: prep (4-way t-split) — A_T fp32 + bf16 MFMA B-fragments ----
// 4 threads per (b,d); q=tid&3 owns t-quarter 4q..4q+3. S assembled via shfl_xor.
__global__ __launch_bounds__(256) void prep_kernel(const float* __restrict__ x,
                                                   float* __restrict__ A_T,
                                                   short* __restrict__ frag,
                                                   float* __restrict__ out0) {
    int g = blockIdx.x * 256 + threadIdx.x;      // 0..98303
    int pair = g >> 2, q = g & 3;
    int b = pair / DIN;
    int d = pair - b * DIN;
    const float* xp = x + (size_t)b * TD + d;

    float v0 = xp[(4 * q + 0) * DIN];
    float v1 = xp[(4 * q + 1) * DIN];
    float v2 = xp[(4 * q + 2) * DIN];
    float v3 = xp[(4 * q + 3) * DIN];
    float S = v0 + v1 + v2 + v3;
    S += __shfl_xor(S, 1, 64);
    S += __shfl_xor(S, 2, 64);
    float xf = __shfl_xor(v0, 1, 64);            // q1 <- q0's x[b,0,d]
    float xl = __shfl_xor(v3, 1, 64);            // q2 <- q3's x[b,15,d]

    int base = d * 96 + b;                       // (d*3+j)*32 + b
    int k0 = 3 * d;
    if (q == 0) {
        A_T[base + 32] = S;                      // j=1
    } else if (q == 1) {
        float u2 = S - xf;                       // j=2
        A_T[base + 64] = u2;
        frag_store(frag, k0 + 2, b, u2);
    } else if (q == 2) {
        float u0 = S - xl;                       // j=0
        A_T[base] = u0;
        frag_store(frag, k0, b, u0);
    } else {
        frag_store(frag, k0 + 1, b, S);          // j=1
    }
    if (g == 0) *out0 = 0.f;
}

// ---- Kernel 2: encode GEMM via MFMA 16x16x32 bf16 — no LDS, no barriers ----
// grid 512 x 256: wave = one 16-row W strip x one k-half. Per chunk:
// 2 global float4 (W fp32) -> cvt bf16 -> A-op; 2 frag b128 (L2) -> B-op; 2 MFMA.
__global__ __launch_bounds__(256, 4) void enc_mfma_kernel(
    const float* __restrict__ W,      // conv_w (16384 x 2304)
    const short* __restrict__ frag,   // (72 x 2 x 64 x 8) bf16
    float* __restrict__ partial)      // (2 x 32 x 16384)
{
    const int tid  = threadIdx.x;
    const int bid  = blockIdx.x;
    const int ks   = bid & 1;
    const int l    = tid & 63;
    const int w    = tid >> 6;
    const int strip = (bid >> 1) * 4 + w;        // 0..1023
    const int s0    = strip << 4;
    const int row   = s0 + (l & 15);
    const int klane = (l >> 4) << 3;

    const float* wrow = W + (size_t)row * KTOT;

    f32x4 acc0 = {0.f, 0.f, 0.f, 0.f};
    f32x4 acc1 = {0.f, 0.f, 0.f, 0.f};

    #pragma unroll 2
    for (int ch = 0; ch < NCH; ++ch) {
        const int cg = ks * NCH + ch;
        const int kb = (cg << 5) + klane;
        const float4 wa = *(const float4*)&wrow[kb];
        const float4 wb = *(const float4*)&wrow[kb + 4];
        bf16x8 wf;
        wf[0] = f2bf(wa.x); wf[1] = f2bf(wa.y); wf[2] = f2bf(wa.z); wf[3] = f2bf(wa.w);
        wf[4] = f2bf(wb.x); wf[5] = f2bf(wb.y); wf[6] = f2bf(wb.z); wf[7] = f2bf(wb.w);
        const bf16x8 a0 = *(const bf16x8*)&frag[((size_t)(cg * 2    ) * 64 + l) * 8];
        const bf16x8 a1 = *(const bf16x8*)&frag[((size_t)(cg * 2 + 1) * 64 + l) * 8];
        acc0 = __builtin_amdgcn_mfma_f32_16x16x32_bf16(wf, a0, acc0, 0, 0, 0);
        acc1 = __builtin_amdgcn_mfma_f32_16x16x32_bf16(wf, a1, acc1, 0, 0, 0);
    }

    // C/D: col=lane&15 (b), row=(lane>>4)*4+reg (s)  [m89]
    const int bcol  = l & 15;
    const int sbase = s0 + ((l >> 4) << 2);
    float* p0 = partial + ((size_t)(ks * 32) + bcol) * DSAE + sbase;
    float* p1 = p0 + (size_t)16 * DSAE;
    #pragma unroll
    for (int r = 0; r < 4; ++r) { p0[r] = acc0[r]; p1[r] = acc1[r]; }
}

// ---- Kernel 3: fused combine + radix top-64 + exact fp32 refine + scatter ----
__global__ __launch_bounds__(1024, 1) void topk_kernel(
    const float* __restrict__ partial, // (2 x 32 x 16384)
    const float* __restrict__ b_enc,
    float* __restrict__ z,             // out: sparse z (32 x DSAE)
    const float* __restrict__ A_T,     // (2304 x 32) fp32 exact
    const float* __restrict__ W,       // conv_w
    float* __restrict__ sel_val,
    int*   __restrict__ sel_idx)
{
    __shared__ unsigned hist[256];
    __shared__ unsigned gsfx[65];
    __shared__ unsigned sfx[257];
    __shared__ int      sdelta;
    __shared__ unsigned scnt;
    __shared__ int      l_idx[CAND];
    __shared__ float    ex_val[CAND];
    __shared__ int      rnk[CAND];
    __shared__ int      eq_min;
    __shared__ float    A_col[KTOT];

    const int t = threadIdx.x;
    const int b = blockIdx.x;
    float* zrow = z + (size_t)b * DSAE;

    // combine in registers: pre = b_enc + partial0 + partial1
    unsigned u[16];
    #pragma unroll
    for (int i = 0; i < 16; ++i) {
        const int col = t + (i << 10);
        float f = b_enc[col]
                + partial[(size_t)b * DSAE + col]
                + partial[(size_t)(32 + b) * DSAE + col];
        unsigned xb = __float_as_uint(f);
        u[i] = (xb & 0x80000000u) ? ~xb : (xb | 0x80000000u);
    }

    // ---- phase A: radix-select the CAND-th largest mapped value ----
    unsigned prefix = 0, pmask = 0;
    int need = CAND;
    for (int p = 0; p < 4; ++p) {
        const int shift = 24 - 8 * p;
        if (t < 256) hist[t] = 0;
        __syncthreads();
        #pragma unroll
        for (int i = 0; i < 16; ++i)
            if ((u[i] & pmask) == prefix)
                atomicAdd(&hist[(u[i] >> shift) & 255u], 1u);
        __syncthreads();
        if (t < 64) {
            unsigned s4 = hist[4*t] + hist[4*t+1] + hist[4*t+2] + hist[4*t+3];
            #pragma unroll
            for (int off = 1; off < 64; off <<= 1) {
                unsigned o = __shfl_down(s4, off, 64);
                if (t + off < 64) s4 += o;
            }
            gsfx[t] = s4;
            if (t == 0) gsfx[64] = 0;
        }
        __syncthreads();
        if (t < 256) {
            int q = t >> 2;
            unsigned acc = gsfx[q + 1];
            for (int d = 4*q + 3; d >= t; --d) acc += hist[d];
            sfx[t] = acc;
            if (t == 0) sfx[256] = 0;
        }
        __syncthreads();
        if (t < 256) {
            if (sfx[t] >= (unsigned)need && sfx[t + 1] < (unsigned)need) sdelta = t;
        }
        __syncthreads();
        const int dlt = sdelta;
        need  -= (int)sfx[dlt + 1];
        prefix |= ((unsigned)dlt) << shift;
        pmask  |= 0xFFu << shift;
        __syncthreads();
    }

    const unsigned ustar = prefix;
    if (t == 0) scnt = 0;
    __syncthreads();
    unsigned eqmask = 0;
    #pragma unroll
    for (int i = 0; i < 16; ++i) {
        int idx = t + (i << 10);
        if (u[i] > ustar) {
            unsigned s = atomicAdd(&scnt, 1u);
            l_idx[s] = idx;
        } else if (u[i] == ustar) {
            eqmask |= (1u << i);
        }
    }
    __syncthreads();
    const int needf = need;
    for (int r = 0; r < needf; ++r) {
        if (t == 0) eq_min = 0x7FFFFFFF;
        __syncthreads();
        #pragma unroll
        for (int i = 0; i < 16; ++i)
            if (eqmask & (1u << i)) atomicMin(&eq_min, t + (i << 10));
        __syncthreads();
        #pragma unroll
        for (int i = 0; i < 16; ++i)
            if ((eqmask & (1u << i)) && (t + (i << 10) == eq_min)) {
                eqmask &= ~(1u << i);
                unsigned s = atomicAdd(&scnt, 1u);
                l_idx[s] = eq_min;
            }
        __syncthreads();
    }

    // ---- stage A_T column b into LDS ----
    for (int q = t; q < KTOT; q += 1024) A_col[q] = A_T[q * 32 + b];
    __syncthreads();

    // ---- phase B: exact fp32 recompute of the 64 candidates ----
    {
        const int j = t >> 4, t16 = t & 15;
        const int cand = l_idx[j];
        const float* wr = W + (size_t)cand * KTOT;
        float s = 0.f;
        for (int q = t16; q < 576; q += 16) {
            const float4 wv = *(const float4*)&wr[q << 2];
            const int k4 = q << 2;
            s += wv.x * A_col[k4] + wv.y * A_col[k4 + 1]
               + wv.z * A_col[k4 + 2] + wv.w * A_col[k4 + 3];
        }
        s += __shfl_xor(s, 1, 64);
        s += __shfl_xor(s, 2, 64);
        s += __shfl_xor(s, 4, 64);
        s += __shfl_xor(s, 8, 64);
        if (t16 == 0) ex_val[j] = s + b_enc[cand];
    }
    __syncthreads();

    // ---- phase C: exact rank (value desc, idx asc), zero z, scatter ----
    if (t < CAND) {
        float v = ex_val[t]; int ix = l_idx[t];
        int r = 0;
        for (int j2 = 0; j2 < CAND; ++j2) {
            float v2 = ex_val[j2]; int ix2 = l_idx[j2];
            r += (v2 > v || (v2 == v && ix2 < ix)) ? 1 : 0;
        }
        rnk[t] = r;
    }
    __syncthreads();
    #pragma unroll
    for (int i = 0; i < 16; ++i) zrow[t + (i << 10)] = 0.f;
    __syncthreads();
    if (t < CAND && rnk[t] < K_) {
        int ix = l_idx[t];
        float v = ex_val[t];
        int pos = 0;
        for (int j2 = 0; j2 < CAND; ++j2)
            pos += (rnk[j2] < K_ && l_idx[j2] < ix) ? 1 : 0;
        float val = v > 0.f ? v : 0.f;
        zrow[ix] = val;
        sel_val[(b << 5) + pos] = val;
        sel_idx[(b << 5) + pos] = ix;
    }
}

// ---- Kernel 4: sparse decode + fused sq-err, atomic loss ----
__global__ __launch_bounds__(256, 4) void decode_kernel(
    const float* __restrict__ W_dec,
    const float* __restrict__ b_dec,
    const float* __restrict__ x,
    const float* __restrict__ sel_val,
    const int*   __restrict__ sel_idx,
    float* __restrict__ xhat,          // d_out + 1
    float* __restrict__ out0)
{
    __shared__ float sv[K_];
    __shared__ int   si[K_];
    __shared__ float wsum[4];

    const int t     = threadIdx.x;
    const int blk   = blockIdx.x;
    const int b     = blk / 12;
    const int chunk = blk - b * 12;

    if (t < K_) { sv[t] = sel_val[(b << 5) + t]; si[t] = sel_idx[(b << 5) + t]; }
    __syncthreads();

    const int e = chunk * 1024 + t * 4;
    float4 acc = *(const float4*)&b_dec[e];
    #pragma unroll 8
    for (int j = 0; j < K_; ++j) {
        const float val = sv[j];
        const float4 wd = *(const float4*)&W_dec[(size_t)si[j] * TD + e];
        acc.x += val * wd.x;
        acc.y += val * wd.y;
        acc.z += val * wd.z;
        acc.w += val * wd.w;
    }

    const size_t xo = (size_t)b * TD + e;
    xhat[xo + 0] = acc.x;
    xhat[xo + 1] = acc.y;
    xhat[xo + 2] = acc.z;
    xhat[xo + 3] = acc.w;

    const float4 xv = *(const float4*)&x[xo];
    float dx = acc.x - xv.x, dy = acc.y - xv.y;
    float dz = acc.z - xv.z, dw = acc.w - xv.w;
    float ss = dx * dx + dy * dy + dz * dz + dw * dw;
    #pragma unroll
    for (int off = 32; off > 0; off >>= 1) ss += __shfl_down(ss, off, 64);
    if ((t & 63) == 0) wsum[t >> 6] = ss;
    __syncthreads();
    if (t == 0)
        atomicAdd(out0, (wsum[0] + wsum[1] + wsum[2] + wsum[3]) * (1.0f / 512.0f));
}

extern "C" void kernel_launch(void* const* d_in, const int* in_sizes, int n_in,
                              void* d_out, int out_size, void* d_ws, size_t ws_size,
                              hipStream_t stream) {
    const float* x      = (const float*)d_in[0];
    const float* conv_w = (const float*)d_in[1];
    const float* b_enc  = (const float*)d_in[2];
    const float* W_dec  = (const float*)d_in[3];
    const float* b_dec  = (const float*)d_in[4];

    float* out  = (float*)d_out;
    float* xhat = out + 1;                        // (32,16,768)
    float* z    = out + 1 + 393216;               // (32,16384)

    float* partial_enc = (float*)d_ws;                           // 4.2 MB
    float* A_T         = (float*)((char*)d_ws + (6u << 20));     // 288 KB
    short* frag        = (short*)((char*)d_ws + (7u << 20));     // 147 KB
    float* sel_val     = (float*)((char*)d_ws + (8u << 20));
    int*   sel_idx     = (int*)  ((char*)d_ws + (8u << 20) + 4096);

    prep_kernel    <<<384, 256,  0, stream>>>(x, A_T, frag, out);
    enc_mfma_kernel<<<512, 256,  0, stream>>>(conv_w, frag, partial_enc);
    topk_kernel    <<<32,  1024, 0, stream>>>(partial_enc, b_enc, z, A_T, conv_w,
                                              sel_val, sel_idx);
    decode_kernel  <<<384, 256,  0, stream>>>(W_dec, b_dec, x, sel_val, sel_idx, xhat, out);
}